// Round 1
// baseline (959.467 us; speedup 1.0000x reference)
//
#include <hip/hip_runtime.h>
#include <hip/hip_bf16.h>

#define IMP -10000.0f

// ws layout (bytes), all offsets 256-aligned
#define O_WT     0u            // 512*120 floats  = 245760 B
#define O_LEN    245760u       // 64 ints
#define O_LOGITS 246016u       // 65536*120 floats = 31457280 B
#define O_ALPHA  31703296u     // 1024*1536*5 floats = 31457280 B
// total ~63.2 MB

// ---------------- prep: lengths from mask (dtype auto-detect) + zero d_out ---
__global__ __launch_bounds__(256) void prep_kernel(const unsigned char* __restrict__ mask,
                                                   int* __restrict__ lens,
                                                   float* __restrict__ out) {
    int n = blockIdx.x;
    int tid = threadIdx.x;
    // mask[0][1] is always true (len >= 512). u8 layout -> byte1==1; i32 -> byte1==0.
    bool i32 = (mask[1] == 0);
    int cnt = 0;
    if (i32) {
        const int* m = (const int*)mask;
        for (int t = tid; t < 1024; t += 256) cnt += (m[n * 1024 + t] != 0);
    } else {
        for (int t = tid; t < 1024; t += 256) cnt += (mask[n * 1024 + t] != 0);
    }
    __shared__ int red[256];
    red[tid] = cnt;
    __syncthreads();
    for (int s = 128; s > 0; s >>= 1) {
        if (tid < s) red[tid] += red[tid + s];
        __syncthreads();
    }
    if (tid == 0) {
        lens[n] = red[0];
        if (n == 0) out[0] = 0.0f;
    }
}

// ---------------- transpose W[120][512] -> Wt[512][120] -----------------------
__global__ __launch_bounds__(256) void transpose_kernel(const float* __restrict__ W,
                                                        float* __restrict__ Wt) {
    int idx = blockIdx.x * 256 + threadIdx.x;
    if (idx >= 512 * 120) return;
    int k = idx / 120, c = idx - k * 120;
    Wt[idx] = W[c * 512 + k];
}

// ---------------- GEMM: C[65536][120] = A[65536][512] @ Wt + bias -------------
__global__ __launch_bounds__(128) void gemm_kernel(const float* __restrict__ A,
                                                   const float* __restrict__ Wt,
                                                   const float* __restrict__ bias,
                                                   float* __restrict__ C) {
    __shared__ float As[64][68];  // [k][row], pad 64->68 to break bank conflicts
    int tid = threadIdx.x;
    long r0 = (long)blockIdx.x * 64;
    int rg = tid / 15;          // 0..7 for active threads
    int cg = tid - rg * 15;     // 0..14
    bool active = tid < 120;

    float acc[8][8];
#pragma unroll
    for (int i = 0; i < 8; ++i)
#pragma unroll
        for (int j = 0; j < 8; ++j) acc[i][j] = 0.f;

    for (int chunk = 0; chunk < 8; ++chunk) {
        int k0 = chunk * 64;
        // stage A tile (64 rows x 64 k), transposed into LDS
#pragma unroll
        for (int i = 0; i < 8; ++i) {
            int flat = tid + i * 128;        // 0..1023
            int row = flat >> 4;
            int kq = (flat & 15) * 4;
            const float4 v = *(const float4*)(A + (r0 + row) * 512 + k0 + kq);
            As[kq + 0][row] = v.x;
            As[kq + 1][row] = v.y;
            As[kq + 2][row] = v.z;
            As[kq + 3][row] = v.w;
        }
        __syncthreads();
        if (active) {
            const float* wp = Wt + (size_t)k0 * 120 + cg * 8;
#pragma unroll 4
            for (int k = 0; k < 64; ++k) {
                float4 a0 = *(const float4*)(&As[k][rg * 8]);
                float4 a1 = *(const float4*)(&As[k][rg * 8 + 4]);
                float4 b0 = *(const float4*)(wp + (size_t)k * 120);
                float4 b1 = *(const float4*)(wp + (size_t)k * 120 + 4);
                float av[8] = {a0.x, a0.y, a0.z, a0.w, a1.x, a1.y, a1.z, a1.w};
                float bv[8] = {b0.x, b0.y, b0.z, b0.w, b1.x, b1.y, b1.z, b1.w};
#pragma unroll
                for (int i = 0; i < 8; ++i)
#pragma unroll
                    for (int j = 0; j < 8; ++j)
                        acc[i][j] = fmaf(av[i], bv[j], acc[i][j]);
            }
        }
        __syncthreads();
    }
    if (active) {
        float bv[8];
#pragma unroll
        for (int j = 0; j < 8; ++j) bv[j] = bias[cg * 8 + j];
#pragma unroll
        for (int i = 0; i < 8; ++i) {
            long r = r0 + rg * 8 + i;
            float4 o0, o1;
            o0.x = acc[i][0] + bv[0]; o0.y = acc[i][1] + bv[1];
            o0.z = acc[i][2] + bv[2]; o0.w = acc[i][3] + bv[3];
            o1.x = acc[i][4] + bv[4]; o1.y = acc[i][5] + bv[5];
            o1.z = acc[i][6] + bv[6]; o1.w = acc[i][7] + bv[7];
            *(float4*)(C + r * 120 + cg * 8) = o0;
            *(float4*)(C + r * 120 + cg * 8 + 4) = o1;
        }
    }
}

// ---------------- CRF forward scan -------------------------------------------
// states: O=0 I=1 B=2 L=3 U=4. into {O,B,U}: LSE(a0,a3,a4); into {I,L}: LSE(a1,a2)
__device__ __forceinline__ void crf_fwd_step(float e0, float e1, float e2, float e3, float e4,
                                             float& a0, float& a1, float& a2, float& a3, float& a4) {
    float m1 = fmaxf(fmaxf(a0, a3), a4);
    float LA = m1 + __logf(__expf(a0 - m1) + __expf(a3 - m1) + __expf(a4 - m1));
    float m2 = fmaxf(a1, a2);
    float LB = m2 + __logf(__expf(a1 - m2) + __expf(a2 - m2));
    a0 = LA + e0; a1 = LB + e1; a2 = LA + e2; a3 = LB + e3; a4 = LA + e4;
}

__global__ __launch_bounds__(64) void fwd_kernel(const float* __restrict__ logits,
                                                 const int* __restrict__ lens,
                                                 float* __restrict__ alphas) {
    int s = blockIdx.x * 64 + threadIdx.x;   // 0..1535
    int n = s / 24;
    int l = s - n * 24;
    int len = lens[n];
    const float* eb = logits + (size_t)n * 1024 * 120 + l * 5;
    float* ab = alphas + s * 5;              // alphas[t][s][k] = alphas[t*7680 + s*5 + k]

    float a0 = eb[0], a1 = eb[1] + IMP, a2 = eb[2], a3 = eb[3] + IMP, a4 = eb[4];
    ab[0] = a0; ab[1] = a1; ab[2] = a2; ab[3] = a3; ab[4] = a4;

    float pe[4][5];
#pragma unroll
    for (int j = 0; j < 4; ++j)
#pragma unroll
        for (int k = 0; k < 5; ++k) pe[j][k] = eb[(size_t)(1 + j) * 120 + k];

    int t = 1;
    for (; t + 4 <= len; t += 4) {
        float ne[4][5];
#pragma unroll
        for (int j = 0; j < 4; ++j)
#pragma unroll
            for (int k = 0; k < 5; ++k) ne[j][k] = eb[(size_t)(t + 4 + j) * 120 + k];
#pragma unroll
        for (int j = 0; j < 4; ++j) {
            crf_fwd_step(pe[j][0], pe[j][1], pe[j][2], pe[j][3], pe[j][4], a0, a1, a2, a3, a4);
            float* ap = ab + (size_t)(t + j) * 7680;
            ap[0] = a0; ap[1] = a1; ap[2] = a2; ap[3] = a3; ap[4] = a4;
        }
#pragma unroll
        for (int j = 0; j < 4; ++j)
#pragma unroll
            for (int k = 0; k < 5; ++k) pe[j][k] = ne[j][k];
    }
    for (; t < len; ++t) {
        const float* ep = eb + (size_t)t * 120;
        crf_fwd_step(ep[0], ep[1], ep[2], ep[3], ep[4], a0, a1, a2, a3, a4);
        float* ap = ab + (size_t)t * 7680;
        ap[0] = a0; ap[1] = a1; ap[2] = a2; ap[3] = a3; ap[4] = a4;
    }
}

// ---------------- CRF backward scan + fused loss ------------------------------
// from O/L/U: LSE over j in {0,2,4}; from I/B: LSE over j in {1,3}
__device__ __forceinline__ void crf_bwd_step(float e0, float e1, float e2, float e3, float e4,
                                             float& b0, float& b1, float& b2, float& b3, float& b4) {
    float p0 = e0 + b0, p1 = e1 + b1, p2 = e2 + b2, p3 = e3 + b3, p4 = e4 + b4;
    float m1 = fmaxf(fmaxf(p0, p2), p4);
    float X = m1 + __logf(__expf(p0 - m1) + __expf(p2 - m1) + __expf(p4 - m1));
    float m2 = fmaxf(p1, p3);
    float Y = m2 + __logf(__expf(p1 - m2) + __expf(p3 - m2));
    b0 = X; b1 = Y; b2 = Y; b3 = X; b4 = X;
}

// replicates: logsumexp_k( where(k==tag, log_softmax(v)[k], IMP) )
__device__ __forceinline__ float loss_term(const float a[5], float b0, float b1, float b2,
                                           float b3, float b4, int tag) {
    float v0 = a[0] + b0, v1 = a[1] + b1, v2 = a[2] + b2, v3 = a[3] + b3, v4 = a[4] + b4;
    float m = fmaxf(fmaxf(fmaxf(fmaxf(v0, v1), v2), v3), v4);
    float ssum = ((((__expf(v0 - m) + __expf(v1 - m)) + __expf(v2 - m)) + __expf(v3 - m)) +
                  __expf(v4 - m));
    float lse = m + __logf(ssum);
    float vt = (tag == 0) ? v0 : (tag == 1) ? v1 : (tag == 2) ? v2 : (tag == 3) ? v3 : v4;
    float ls = vt - lse;  // log_softmax at target; can be ~ -1e4 at boundaries!
    float mm = fmaxf(ls, IMP);
    float ss = __expf(ls - mm) + 4.0f * __expf(IMP - mm);
    return mm + __logf(ss);
}

__global__ __launch_bounds__(64) void bwd_kernel(const float* __restrict__ logits,
                                                 const int* __restrict__ lens,
                                                 const float* __restrict__ alphas,
                                                 const int* __restrict__ tags,
                                                 float* __restrict__ out) {
    int s = blockIdx.x * 64 + threadIdx.x;
    int n = s / 24, l = s - n * 24;
    int len = lens[n];
    const float* eb = logits + (size_t)n * 1024 * 120 + l * 5;
    const float* ab = alphas + s * 5;
    const int* tg = tags + (size_t)s * 1024;

    float b0 = 0.f, b1 = IMP, b2 = IMP, b3 = 0.f, b4 = 0.f;  // end vector
    float L = 0.f;
    {
        int t = len - 1;
        float a[5];
#pragma unroll
        for (int k = 0; k < 5; ++k) a[k] = ab[(size_t)t * 7680 + k];
        L += loss_term(a, b0, b1, b2, b3, b4, tg[t]);
    }

    int t = len - 2;
    float pe[4][5], pa[4][5];
    int pt[4];
#pragma unroll
    for (int j = 0; j < 4; ++j) {
        int ti = t - j; int tc = ti < 0 ? 0 : ti;
#pragma unroll
        for (int k = 0; k < 5; ++k) {
            pe[j][k] = eb[(size_t)(tc + 1) * 120 + k];
            pa[j][k] = ab[(size_t)tc * 7680 + k];
        }
        pt[j] = tg[tc];
    }
    for (; t >= 3; t -= 4) {
        float ne[4][5], na[4][5];
        int nt[4];
#pragma unroll
        for (int j = 0; j < 4; ++j) {
            int ti = t - 4 - j; int tc = ti < 0 ? 0 : ti;
#pragma unroll
            for (int k = 0; k < 5; ++k) {
                ne[j][k] = eb[(size_t)(tc + 1) * 120 + k];
                na[j][k] = ab[(size_t)tc * 7680 + k];
            }
            nt[j] = tg[tc];
        }
#pragma unroll
        for (int j = 0; j < 4; ++j) {
            crf_bwd_step(pe[j][0], pe[j][1], pe[j][2], pe[j][3], pe[j][4], b0, b1, b2, b3, b4);
            L += loss_term(pa[j], b0, b1, b2, b3, b4, pt[j]);
        }
#pragma unroll
        for (int j = 0; j < 4; ++j) {
#pragma unroll
            for (int k = 0; k < 5; ++k) { pe[j][k] = ne[j][k]; pa[j][k] = na[j][k]; }
            pt[j] = nt[j];
        }
    }
    for (; t >= 0; --t) {
        const float* ep = eb + (size_t)(t + 1) * 120;
        crf_bwd_step(ep[0], ep[1], ep[2], ep[3], ep[4], b0, b1, b2, b3, b4);
        float a[5];
#pragma unroll
        for (int k = 0; k < 5; ++k) a[k] = ab[(size_t)t * 7680 + k];
        L += loss_term(a, b0, b1, b2, b3, b4, tg[t]);
    }
    atomicAdd(out, -L * 0.01f);
}

// ---------------- launcher ----------------------------------------------------
extern "C" void kernel_launch(void* const* d_in, const int* in_sizes, int n_in,
                              void* d_out, int out_size, void* d_ws, size_t ws_size,
                              hipStream_t stream) {
    const float* embeds = (const float*)d_in[0];
    const float* W = (const float*)d_in[1];
    const float* bias = (const float*)d_in[2];
    const unsigned char* mask = (const unsigned char*)d_in[3];
    const int* tags = (const int*)d_in[4];
    float* out = (float*)d_out;

    char* ws = (char*)d_ws;
    float* Wt = (float*)(ws + O_WT);
    int* lens = (int*)(ws + O_LEN);
    float* logits = (float*)(ws + O_LOGITS);
    float* alphas = (float*)(ws + O_ALPHA);

    prep_kernel<<<64, 256, 0, stream>>>(mask, lens, out);
    transpose_kernel<<<240, 256, 0, stream>>>(W, Wt);
    gemm_kernel<<<1024, 128, 0, stream>>>(embeds, Wt, bias, logits);
    fwd_kernel<<<24, 64, 0, stream>>>(logits, lens, alphas);
    bwd_kernel<<<24, 64, 0, stream>>>(logits, lens, alphas, tags, out);
}

// Round 7
// 365.064 us; speedup vs baseline: 2.6282x; 2.6282x over previous
//
#include <hip/hip_runtime.h>
#include <hip/hip_bf16.h>

#define IMP -10000.0f

// ws layout (bytes)
#define O_BH   0u          // Bhi: 128*512 bf16 = 131072
#define O_BL   131072u     // Blo: 131072 -> ends 262144
#define O_LEN  262144u     // 64 ints
#define O_ACC  262400u     // 1 double
#define O_E    262656u     // [1024][1536][5] f = 31457280 -> ends 31719936
#define O_P    31719936u   // [64][1536][4] f = 1572864   -> ends 33292800
#define O_Q    33292800u   // [64][1536][4] f = 1572864   -> ends 34865664
#define O_FS   34865664u   // [64][1536][2] f = 786432    -> ends 35652096
#define O_BS   35652096u   // [64][1536][2] f = 786432    -> ends 36438528

typedef __attribute__((ext_vector_type(8))) short bf16x8;
typedef __attribute__((ext_vector_type(4))) float f32x4;

__device__ __forceinline__ float lse2(float a, float b) {
    float m = fmaxf(a, b);
    return m + __logf(__expf(a - m) + __expf(b - m));
}

// float -> bf16 round-to-nearest-even (bit trick; inputs are finite)
__device__ __forceinline__ unsigned short f2bf(float x) {
    unsigned u = __float_as_uint(x);
    return (unsigned short)((u + 0x7FFFu + ((u >> 16) & 1u)) >> 16);
}
__device__ __forceinline__ float bf2f(unsigned short h) {
    return __uint_as_float(((unsigned)h) << 16);
}

// ---------------- prep: lengths from mask + zero accumulator ------------------
__global__ __launch_bounds__(256) void prep_kernel(const unsigned char* __restrict__ mask,
                                                   int* __restrict__ lens,
                                                   double* __restrict__ acc) {
    int n = blockIdx.x;
    int tid = threadIdx.x;
    bool i32 = (mask[1] == 0);  // mask[0][1] always true (len>=512): u8->1, i32->byte1==0
    int cnt = 0;
    if (i32) {
        const int* m = (const int*)mask;
        for (int t = tid; t < 1024; t += 256) cnt += (m[n * 1024 + t] != 0);
    } else {
        for (int t = tid; t < 1024; t += 256) cnt += (mask[n * 1024 + t] != 0);
    }
    __shared__ int red[256];
    red[tid] = cnt;
    __syncthreads();
    for (int s = 128; s > 0; s >>= 1) {
        if (tid < s) red[tid] += red[tid + s];
        __syncthreads();
    }
    if (tid == 0) {
        lens[n] = red[0];
        if (n == 0) *acc = 0.0;
    }
}

// ---------------- W -> split bf16, B-fragment-swizzled layout -----------------
// element (col,k) -> flat ((kt*8+ct)*64 + kg*16 + c)*8 + i
// with ct=col>>4, c=col&15, kt=k>>5, kg=(k>>3)&3, i=k&7. cols 120..127 zero-pad.
__global__ __launch_bounds__(256) void prepW_kernel(const float* __restrict__ W,
                                                    short* __restrict__ Bh,
                                                    short* __restrict__ Bl) {
    int idx = blockIdx.x * 256 + threadIdx.x;  // 0..65535
    int col = idx >> 9, k = idx & 511;
    float v = (col < 120) ? W[col * 512 + k] : 0.f;
    unsigned short h = f2bf(v);
    unsigned short l = f2bf(v - bf2f(h));
    int ct = col >> 4, c = col & 15;
    int kt = k >> 5, kg = (k >> 3) & 3, i = k & 7;
    size_t flat = ((size_t)(kt * 8 + ct) * 64 + kg * 16 + c) * 8 + i;
    Bh[flat] = (short)h;
    Bl[flat] = (short)l;
}

// ---------------- split-bf16 MFMA GEMM: E = embeds @ W^T + bias ---------------
// block: 128 rows x 128 cols (120 valid), 4 waves, each wave 8 row-tiles x 2 col-tiles.
// 3 products: ahi*bhi + ahi*blo + alo*bhi (~fp32-16bit precision).
__global__ __launch_bounds__(256) void mfma_gemm(const float* __restrict__ A,
                                                 const short* __restrict__ Bh,
                                                 const short* __restrict__ Bl,
                                                 const float* __restrict__ bias,
                                                 float* __restrict__ E) {
    __shared__ short Ah[4][128][8];  // [kg][row][8 k] bf16-hi, 8 KB
    __shared__ short Al[4][128][8];  // bf16-lo
    int tid = threadIdx.x;
    int wave = tid >> 6, lane = tid & 63;
    long r0 = (long)blockIdx.x * 128;

    f32x4 acc[8][2];
#pragma unroll
    for (int rt = 0; rt < 8; ++rt)
#pragma unroll
        for (int ci = 0; ci < 2; ++ci) {
            acc[rt][ci][0] = 0.f; acc[rt][ci][1] = 0.f;
            acc[rt][ci][2] = 0.f; acc[rt][ci][3] = 0.f;
        }

    float bb[2];
#pragma unroll
    for (int ci = 0; ci < 2; ++ci) {
        int col = wave * 32 + ci * 16 + (lane & 15);
        bb[ci] = (col < 120) ? bias[col] : 0.f;
    }

    int arow = lane & 15;
    int akg = lane >> 4;

    for (int kt = 0; kt < 16; ++kt) {
        __syncthreads();  // protect LDS from previous iteration's readers
        // stage A tile: 128 rows x 32 k, fused fp32 -> (hi,lo) bf16 split
#pragma unroll
        for (int i = 0; i < 4; ++i) {
            int f = tid + (i << 8);          // 0..1023
            int row = f >> 3, fq = f & 7;    // fq: which float4 in the row's 32 k
            const float4 v = *(const float4*)(A + (r0 + row) * 512 + kt * 32 + fq * 4);
            int kgw = fq >> 1, i0 = (fq & 1) * 4;
            unsigned short h0 = f2bf(v.x), h1 = f2bf(v.y), h2 = f2bf(v.z), h3 = f2bf(v.w);
            short4 hv = make_short4((short)h0, (short)h1, (short)h2, (short)h3);
            short4 lv = make_short4((short)f2bf(v.x - bf2f(h0)), (short)f2bf(v.y - bf2f(h1)),
                                    (short)f2bf(v.z - bf2f(h2)), (short)f2bf(v.w - bf2f(h3)));
            *(short4*)&Ah[kgw][row][i0] = hv;
            *(short4*)&Al[kgw][row][i0] = lv;
        }
        __syncthreads();

        // B fragments from global (L2-resident, pre-swizzled): 16B/lane coalesced
        bf16x8 bh[2], bl[2];
#pragma unroll
        for (int ci = 0; ci < 2; ++ci) {
            int ct = wave * 2 + ci;
            size_t base = ((size_t)(kt * 8 + ct) * 64 + lane) * 8;
            bh[ci] = *(const bf16x8*)(Bh + base);
            bl[ci] = *(const bf16x8*)(Bl + base);
        }

#pragma unroll
        for (int rt = 0; rt < 8; ++rt) {
            bf16x8 ah = *(const bf16x8*)&Ah[akg][rt * 16 + arow][0];
            bf16x8 al = *(const bf16x8*)&Al[akg][rt * 16 + arow][0];
#pragma unroll
            for (int ci = 0; ci < 2; ++ci) {
                acc[rt][ci] = __builtin_amdgcn_mfma_f32_16x16x32_bf16(ah, bh[ci], acc[rt][ci], 0, 0, 0);
                acc[rt][ci] = __builtin_amdgcn_mfma_f32_16x16x32_bf16(ah, bl[ci], acc[rt][ci], 0, 0, 0);
                acc[rt][ci] = __builtin_amdgcn_mfma_f32_16x16x32_bf16(al, bh[ci], acc[rt][ci], 0, 0, 0);
            }
        }
    }

    // store: C/D layout col=lane&15, row=(lane>>4)*4+reg  [m89/m91-verified]
#pragma unroll
    for (int rt = 0; rt < 8; ++rt) {
#pragma unroll
        for (int ci = 0; ci < 2; ++ci) {
            int col = wave * 32 + ci * 16 + (lane & 15);
            if (col < 120) {
#pragma unroll
                for (int j = 0; j < 4; ++j) {
                    long r = r0 + rt * 16 + (lane >> 4) * 4 + j;  // r = n*1024 + t
                    int n = (int)(r >> 10), t = (int)(r & 1023);
                    E[(size_t)t * 7680 + n * 120 + col] = acc[rt][ci][j] + bb[ci];
                }
            }
        }
    }
}

// ---------------- chunk operators (2x2 log-semiring) --------------------------
// fwd step t: M_t = [[lse2(e0,e4), e3],[e2, e1]] from e_t;  state (x,y)->M*state
// bwd step t: N_t = [[lse2(e0,e4), e2],[e3, e1]] from e_{t+1}
__global__ __launch_bounds__(256) void chunkops_kernel(const float* __restrict__ E,
                                                       const int* __restrict__ lens,
                                                       float* __restrict__ P,
                                                       float* __restrict__ Q,
                                                       float* __restrict__ BS) {
    int s = blockIdx.x * 256 + threadIdx.x;  // 0..1535
    int c = blockIdx.y;                      // 0..63
    int t0 = c << 4;
    const float* ep = E + (size_t)t0 * 7680 + s * 5;

    if (blockIdx.z == 0) {
        // forward chunk operator: P_c = M_{t0+15} (x) ... (x) M_{t0}
        float e0 = ep[0], e1 = ep[1], e2 = ep[2], e3 = ep[3], e4 = ep[4];
        float r00 = lse2(e0, e4), r01 = e3, r10 = e2, r11 = e1;
#pragma unroll
        for (int j = 1; j < 16; ++j) {
            const float* q = ep + (size_t)j * 7680;
            float f0 = q[0], f1 = q[1], f2 = q[2], f3 = q[3], f4 = q[4];
            float m00 = lse2(f0, f4), m01 = f3, m10 = f2, m11 = f1;
            float n00 = lse2(m00 + r00, m01 + r10);
            float n01 = lse2(m00 + r01, m01 + r11);
            float n10 = lse2(m10 + r00, m11 + r10);
            float n11 = lse2(m10 + r01, m11 + r11);
            r00 = n00; r01 = n01; r10 = n10; r11 = n11;
        }
        float4 v; v.x = r00; v.y = r01; v.z = r10; v.w = r11;
        *(float4*)(P + ((size_t)c * 1536 + s) * 4) = v;
    } else {
        int len = lens[s / 24];
        int t1 = t0 + 16;
        if (t1 <= len - 1) {
            // fully active: Q_c = N_{t0} (x) N_{t0+1} (x) ... (x) N_{t1-1}
            const float* q = ep + 7680;  // e_{t0+1}
            float f0 = q[0], f1 = q[1], f2 = q[2], f3 = q[3], f4 = q[4];
            float r00 = lse2(f0, f4), r01 = f2, r10 = f3, r11 = f1;
#pragma unroll
            for (int j = 1; j < 16; ++j) {
                const float* qq = ep + (size_t)(j + 1) * 7680;
                float g0 = qq[0], g1 = qq[1], g2 = qq[2], g3 = qq[3], g4 = qq[4];
                float n00 = lse2(g0, g4), n01 = g2, n10 = g3, n11 = g1;
                float m00 = lse2(r00 + n00, r01 + n10);
                float m01 = lse2(r00 + n01, r01 + n11);
                float m10 = lse2(r10 + n00, r11 + n10);
                float m11 = lse2(r10 + n01, r11 + n11);
                r00 = m00; r01 = m01; r10 = m10; r11 = m11;
            }
            float4 v; v.x = r00; v.y = r01; v.z = r10; v.w = r11;
            *(float4*)(Q + ((size_t)c * 1536 + s) * 4) = v;
        } else if (t0 <= len - 1) {
            // boundary chunk: walk from end-state at len-1 down to t0
            float X = 0.f, Y = IMP;
            for (int t = len - 2; t >= t0; --t) {
                const float* qq = E + (size_t)(t + 1) * 7680 + s * 5;
                float g0 = qq[0], g1 = qq[1], g2 = qq[2], g3 = qq[3], g4 = qq[4];
                float nX = lse2(lse2(g0, g4) + X, g2 + Y);
                float nY = lse2(g3 + X, g1 + Y);
                X = nX; Y = nY;
            }
            float2 v; v.x = X; v.y = Y;
            *(float2*)(BS + ((size_t)c * 1536 + s) * 2) = v;
        }
    }
}

// ---------------- sequential combine over 64 chunks per sequence --------------
__global__ __launch_bounds__(64) void combine_kernel(const float* __restrict__ P,
                                                     const float* __restrict__ Q,
                                                     const int* __restrict__ lens,
                                                     float* __restrict__ FS,
                                                     float* __restrict__ BS) {
    int s = blockIdx.x * 64 + threadIdx.x;
    // forward prefix: FS[c] = state at t = c*16
    float x = 0.f, y = IMP;
    for (int c = 0; c < 64; ++c) {
        float2 v; v.x = x; v.y = y;
        *(float2*)(FS + ((size_t)c * 1536 + s) * 2) = v;
        float4 p = *(const float4*)(P + ((size_t)c * 1536 + s) * 4);
        float nx = lse2(p.x + x, p.y + y);
        float ny = lse2(p.z + x, p.w + y);
        x = nx; y = ny;
    }
    // backward suffix: BS[c] = beta state at t = c*16 (BS[cb] written by chunkops)
    int len = lens[s / 24];
    int cb = (len - 1) >> 4;
    float2 b = *(const float2*)(BS + ((size_t)cb * 1536 + s) * 2);
    float X = b.x, Y = b.y;
    for (int c = cb - 1; c >= 0; --c) {
        float4 q = *(const float4*)(Q + ((size_t)c * 1536 + s) * 4);
        float nX = lse2(q.x + X, q.y + Y);
        float nY = lse2(q.z + X, q.w + Y);
        X = nX; Y = nY;
        float2 v; v.x = X; v.y = Y;
        *(float2*)(BS + ((size_t)c * 1536 + s) * 2) = v;
    }
}

// ---------------- fused replay + loss -----------------------------------------
__global__ __launch_bounds__(256) void loss_kernel(const float* __restrict__ E,
                                                   const int* __restrict__ lens,
                                                   const float* __restrict__ FS,
                                                   const float* __restrict__ BS,
                                                   const int* __restrict__ tags,
                                                   double* __restrict__ acc) {
    int s = blockIdx.x * 256 + threadIdx.x;
    int c = blockIdx.y;
    int t0 = c << 4;
    int len = lens[s / 24];
    double Lv = 0.0;

    if (t0 < len) {
        int cb = (len - 1) >> 4;
        int nt = min(16, len - t0);
        const float* ep = E + (size_t)t0 * 7680 + s * 5;
        const int* tg = tags + (size_t)s * 1024;

        // forward replay, states in registers
        float2 f = *(const float2*)(FS + ((size_t)c * 1536 + s) * 2);
        float x = f.x, y = f.y;
        float xs[16], ys[16];
#pragma unroll
        for (int j = 0; j < 16; ++j) {
            if (j < nt) {
                xs[j] = x; ys[j] = y;
                const float* q = ep + (size_t)j * 7680;
                float g0 = q[0], g1 = q[1], g2 = q[2], g3 = q[3], g4 = q[4];
                float nx = lse2(lse2(g0, g4) + x, g3 + y);
                float ny = lse2(g2 + x, g1 + y);
                x = nx; y = ny;
            }
        }

        // backward replay + loss
        float X = 0.f, Y = IMP;
        float p0 = 0.f, p1 = 0.f, p2 = 0.f, p3 = 0.f, p4 = 0.f;  // e_{t+1} cache
        if (c < cb) {
            float2 bb = *(const float2*)(BS + ((size_t)(c + 1) * 1536 + s) * 2);
            X = bb.x; Y = bb.y;
            const float* q = ep + (size_t)16 * 7680;  // e[t0+16], valid (<= len-1 <= 1023)
            p0 = q[0]; p1 = q[1]; p2 = q[2]; p3 = q[3]; p4 = q[4];
        }
#pragma unroll
        for (int j = 15; j >= 0; --j) {
            if (j >= nt) continue;
            int t = t0 + j;
            const float* q = ep + (size_t)j * 7680;
            float g0 = q[0], g1 = q[1], g2 = q[2], g3 = q[3], g4 = q[4];
            if (c == cb && j == nt - 1) {
                X = 0.f; Y = IMP;  // beta_{len-1} = end
            } else {
                float nX = lse2(lse2(p0, p4) + X, p2 + Y);
                float nY = lse2(p3 + X, p1 + Y);
                X = nX; Y = nY;
            }
            float v0 = xs[j] + g0 + X, v1 = ys[j] + g1 + Y, v2 = xs[j] + g2 + Y;
            float v3 = ys[j] + g3 + X, v4 = xs[j] + g4 + X;
            int tag = tg[t];
            float m = fmaxf(fmaxf(fmaxf(fmaxf(v0, v1), v2), v3), v4);
            float ssum = __expf(v0 - m) + __expf(v1 - m) + __expf(v2 - m) +
                         __expf(v3 - m) + __expf(v4 - m);
            float lse = m + __logf(ssum);
            float vt = (tag == 0) ? v0 : (tag == 1) ? v1 : (tag == 2) ? v2 : (tag == 3) ? v3 : v4;
            float ls = vt - lse;
            float mm = fmaxf(ls, IMP);
            float term = mm + __logf(__expf(ls - mm) + 4.0f * __expf(IMP - mm));
            Lv += (double)term;
            p0 = g0; p1 = g1; p2 = g2; p3 = g3; p4 = g4;
        }
    }

    __shared__ double red[256];
    red[threadIdx.x] = Lv;
    __syncthreads();
    for (int st = 128; st > 0; st >>= 1) {
        if (threadIdx.x < st) red[threadIdx.x] += red[threadIdx.x + st];
        __syncthreads();
    }
    if (threadIdx.x == 0) atomicAdd(acc, red[0]);
}

__global__ void finalize_kernel(const double* __restrict__ acc, float* __restrict__ out) {
    out[0] = (float)(-(*acc) * 0.01);
}

// ---------------- launcher ----------------------------------------------------
extern "C" void kernel_launch(void* const* d_in, const int* in_sizes, int n_in,
                              void* d_out, int out_size, void* d_ws, size_t ws_size,
                              hipStream_t stream) {
    const float* embeds = (const float*)d_in[0];
    const float* W = (const float*)d_in[1];
    const float* bias = (const float*)d_in[2];
    const unsigned char* mask = (const unsigned char*)d_in[3];
    const int* tags = (const int*)d_in[4];
    float* out = (float*)d_out;

    char* ws = (char*)d_ws;
    short* Bh = (short*)(ws + O_BH);
    short* Bl = (short*)(ws + O_BL);
    int* lens = (int*)(ws + O_LEN);
    double* acc = (double*)(ws + O_ACC);
    float* E = (float*)(ws + O_E);
    float* P = (float*)(ws + O_P);
    float* Q = (float*)(ws + O_Q);
    float* FS = (float*)(ws + O_FS);
    float* BS = (float*)(ws + O_BS);

    prep_kernel<<<64, 256, 0, stream>>>(mask, lens, acc);
    prepW_kernel<<<256, 256, 0, stream>>>(W, Bh, Bl);
    mfma_gemm<<<512, 256, 0, stream>>>(embeds, Bh, Bl, bias, E);
    chunkops_kernel<<<dim3(6, 64, 2), 256, 0, stream>>>(E, lens, P, Q, BS);
    combine_kernel<<<24, 64, 0, stream>>>(P, Q, lens, FS, BS);
    loss_kernel<<<dim3(6, 64), 256, 0, stream>>>(E, lens, FS, BS, tags, acc);
    finalize_kernel<<<1, 1, 0, stream>>>(acc, out);
}

// Round 9
// 329.892 us; speedup vs baseline: 2.9084x; 1.1066x over previous
//
#include <hip/hip_runtime.h>
#include <hip/hip_bf16.h>

#define IMP -10000.0f

// ws layout (bytes)
#define O_BH   0u          // Bhi: 128*512 bf16 = 131072
#define O_BL   131072u     // Blo -> ends 262144
#define O_LEN  262144u     // 64 ints (+pad)
#define O_ACC  262400u     // 1 double (+pad)
#define O_TT   262656u     // tagsT [1024][1536] i32 = 6291456 -> ends 6554112
#define O_E    6554112u    // [1024][1536][5] f = 31457280 -> ends 38011392
#define O_P    38011392u   // [128][1536][4] f = 3145728  -> ends 41157120
#define O_Q    41157120u   // [128][1536][4] f = 3145728  -> ends 44302848
#define O_FS   44302848u   // [128][1536][2] f = 1572864  -> ends 45875712
#define O_BS   45875712u   // [128][1536][2] f = 1572864  -> ends 47448576

typedef __attribute__((ext_vector_type(8))) short bf16x8;
typedef __attribute__((ext_vector_type(4))) float f32x4;

__device__ __forceinline__ float lse2(float a, float b) {
    float m = fmaxf(a, b);
    return m + __logf(__expf(a - m) + __expf(b - m));
}

// float -> bf16 round-to-nearest-even (bit trick; inputs are finite)
__device__ __forceinline__ unsigned short f2bf(float x) {
    unsigned u = __float_as_uint(x);
    return (unsigned short)((u + 0x7FFFu + ((u >> 16) & 1u)) >> 16);
}
__device__ __forceinline__ float bf2f(unsigned short h) {
    return __uint_as_float(((unsigned)h) << 16);
}

// ---------------- prep: lengths from mask + zero accumulator ------------------
__global__ __launch_bounds__(256) void prep_kernel(const unsigned char* __restrict__ mask,
                                                   int* __restrict__ lens,
                                                   double* __restrict__ acc) {
    int n = blockIdx.x;
    int tid = threadIdx.x;
    bool i32 = (mask[1] == 0);  // mask[0][1] always true (len>=512): u8->1, i32->byte1==0
    int cnt = 0;
    if (i32) {
        const int* m = (const int*)mask;
        for (int t = tid; t < 1024; t += 256) cnt += (m[n * 1024 + t] != 0);
    } else {
        for (int t = tid; t < 1024; t += 256) cnt += (mask[n * 1024 + t] != 0);
    }
    __shared__ int red[256];
    red[tid] = cnt;
    __syncthreads();
    for (int s = 128; s > 0; s >>= 1) {
        if (tid < s) red[tid] += red[tid + s];
        __syncthreads();
    }
    if (tid == 0) {
        lens[n] = red[0];
        if (n == 0) *acc = 0.0;
    }
}

// ---------------- tags [s][t] -> tagsT [t][s] (coalesced writes) --------------
__global__ __launch_bounds__(256) void tagsT_kernel(const int* __restrict__ tags,
                                                    int* __restrict__ tagsT) {
    int idx = blockIdx.x * 256 + threadIdx.x;   // 0..1572863
    int t = idx / 1536, s = idx - t * 1536;
    tagsT[idx] = tags[(size_t)s * 1024 + t];
}

// ---------------- W -> split bf16, B-fragment-swizzled layout -----------------
__global__ __launch_bounds__(256) void prepW_kernel(const float* __restrict__ W,
                                                    short* __restrict__ Bh,
                                                    short* __restrict__ Bl) {
    int idx = blockIdx.x * 256 + threadIdx.x;  // 0..65535
    int col = idx >> 9, k = idx & 511;
    float v = (col < 120) ? W[col * 512 + k] : 0.f;
    unsigned short h = f2bf(v);
    unsigned short l = f2bf(v - bf2f(h));
    int ct = col >> 4, c = col & 15;
    int kt = k >> 5, kg = (k >> 3) & 3, i = k & 7;
    size_t flat = ((size_t)(kt * 8 + ct) * 64 + kg * 16 + c) * 8 + i;
    Bh[flat] = (short)h;
    Bl[flat] = (short)l;
}

// ---------------- split-bf16 MFMA GEMM: E = embeds @ W^T + bias ---------------
__global__ __launch_bounds__(256) void mfma_gemm(const float* __restrict__ A,
                                                 const short* __restrict__ Bh,
                                                 const short* __restrict__ Bl,
                                                 const float* __restrict__ bias,
                                                 float* __restrict__ E) {
    __shared__ short Ah[4][128][8];
    __shared__ short Al[4][128][8];
    int tid = threadIdx.x;
    int wave = tid >> 6, lane = tid & 63;
    long r0 = (long)blockIdx.x * 128;

    f32x4 acc[8][2];
#pragma unroll
    for (int rt = 0; rt < 8; ++rt)
#pragma unroll
        for (int ci = 0; ci < 2; ++ci) {
            acc[rt][ci][0] = 0.f; acc[rt][ci][1] = 0.f;
            acc[rt][ci][2] = 0.f; acc[rt][ci][3] = 0.f;
        }

    float bb[2];
#pragma unroll
    for (int ci = 0; ci < 2; ++ci) {
        int col = wave * 32 + ci * 16 + (lane & 15);
        bb[ci] = (col < 120) ? bias[col] : 0.f;
    }

    int arow = lane & 15;
    int akg = lane >> 4;

    for (int kt = 0; kt < 16; ++kt) {
        __syncthreads();
#pragma unroll
        for (int i = 0; i < 4; ++i) {
            int f = tid + (i << 8);
            int row = f >> 3, fq = f & 7;
            const float4 v = *(const float4*)(A + (r0 + row) * 512 + kt * 32 + fq * 4);
            int kgw = fq >> 1, i0 = (fq & 1) * 4;
            unsigned short h0 = f2bf(v.x), h1 = f2bf(v.y), h2 = f2bf(v.z), h3 = f2bf(v.w);
            short4 hv = make_short4((short)h0, (short)h1, (short)h2, (short)h3);
            short4 lv = make_short4((short)f2bf(v.x - bf2f(h0)), (short)f2bf(v.y - bf2f(h1)),
                                    (short)f2bf(v.z - bf2f(h2)), (short)f2bf(v.w - bf2f(h3)));
            *(short4*)&Ah[kgw][row][i0] = hv;
            *(short4*)&Al[kgw][row][i0] = lv;
        }
        __syncthreads();

        bf16x8 bh[2], bl[2];
#pragma unroll
        for (int ci = 0; ci < 2; ++ci) {
            int ct = wave * 2 + ci;
            size_t base = ((size_t)(kt * 8 + ct) * 64 + lane) * 8;
            bh[ci] = *(const bf16x8*)(Bh + base);
            bl[ci] = *(const bf16x8*)(Bl + base);
        }

#pragma unroll
        for (int rt = 0; rt < 8; ++rt) {
            bf16x8 ah = *(const bf16x8*)&Ah[akg][rt * 16 + arow][0];
            bf16x8 al = *(const bf16x8*)&Al[akg][rt * 16 + arow][0];
#pragma unroll
            for (int ci = 0; ci < 2; ++ci) {
                acc[rt][ci] = __builtin_amdgcn_mfma_f32_16x16x32_bf16(ah, bh[ci], acc[rt][ci], 0, 0, 0);
                acc[rt][ci] = __builtin_amdgcn_mfma_f32_16x16x32_bf16(ah, bl[ci], acc[rt][ci], 0, 0, 0);
                acc[rt][ci] = __builtin_amdgcn_mfma_f32_16x16x32_bf16(al, bh[ci], acc[rt][ci], 0, 0, 0);
            }
        }
    }

#pragma unroll
    for (int rt = 0; rt < 8; ++rt) {
#pragma unroll
        for (int ci = 0; ci < 2; ++ci) {
            int col = wave * 32 + ci * 16 + (lane & 15);
            if (col < 120) {
#pragma unroll
                for (int j = 0; j < 4; ++j) {
                    long r = r0 + rt * 16 + (lane >> 4) * 4 + j;  // r = n*1024 + t
                    int n = (int)(r >> 10), t = (int)(r & 1023);
                    E[(size_t)t * 7680 + n * 120 + col] = acc[rt][ci][j] + bb[ci];
                }
            }
        }
    }
}

// ---------------- fused chunk operators, chunk=8 (2x2 log-semiring) -----------
// fwd step t: M_t = [[lse2(e0,e4), e3],[e2, e1]] from e_t;  state' = M*state
// bwd step t: N_t = [[lse2(e0,e4), e2],[e3, e1]] from e_{t+1}; beta_t = N_t*beta_{t+1}
__global__ __launch_bounds__(256) void chunkops_kernel(const float* __restrict__ E,
                                                       const int* __restrict__ lens,
                                                       float* __restrict__ P,
                                                       float* __restrict__ Q,
                                                       float* __restrict__ BS) {
    int s = blockIdx.x * 256 + threadIdx.x;  // 0..1535
    int c = blockIdx.y;                      // 0..127
    int t0 = c << 3;
    int len = lens[s / 24];
    const float* ep = E + (size_t)t0 * 7680 + s * 5;
    bool fullQ = (t0 + 8 <= len - 1);

    float e[9][5];
#pragma unroll
    for (int j = 0; j < 8; ++j) {
        const float* q = ep + (size_t)j * 7680;
        e[j][0] = q[0]; e[j][1] = q[1]; e[j][2] = q[2]; e[j][3] = q[3]; e[j][4] = q[4];
    }
    if (fullQ) {
        const float* q = ep + (size_t)8 * 7680;
        e[8][0] = q[0]; e[8][1] = q[1]; e[8][2] = q[2]; e[8][3] = q[3]; e[8][4] = q[4];
    }

    // forward chunk operator: P_c = M_{t0+7} x ... x M_{t0}
    {
        float r00 = lse2(e[0][0], e[0][4]), r01 = e[0][3], r10 = e[0][2], r11 = e[0][1];
#pragma unroll
        for (int j = 1; j < 8; ++j) {
            float m00 = lse2(e[j][0], e[j][4]), m01 = e[j][3], m10 = e[j][2], m11 = e[j][1];
            float n00 = lse2(m00 + r00, m01 + r10);
            float n01 = lse2(m00 + r01, m01 + r11);
            float n10 = lse2(m10 + r00, m11 + r10);
            float n11 = lse2(m10 + r01, m11 + r11);
            r00 = n00; r01 = n01; r10 = n10; r11 = n11;
        }
        float4 v; v.x = r00; v.y = r01; v.z = r10; v.w = r11;
        *(float4*)(P + ((size_t)c * 1536 + s) * 4) = v;
    }

    if (fullQ) {
        // Q_c = N_{t0} x N_{t0+1} x ... x N_{t0+7}
        float r00 = lse2(e[1][0], e[1][4]), r01 = e[1][2], r10 = e[1][3], r11 = e[1][1];
#pragma unroll
        for (int j = 1; j < 8; ++j) {
            float g0 = e[j + 1][0], g1 = e[j + 1][1], g2 = e[j + 1][2], g3 = e[j + 1][3],
                  g4 = e[j + 1][4];
            float n00 = lse2(g0, g4), n01 = g2, n10 = g3, n11 = g1;
            float m00 = lse2(r00 + n00, r01 + n10);
            float m01 = lse2(r00 + n01, r01 + n11);
            float m10 = lse2(r10 + n00, r11 + n10);
            float m11 = lse2(r10 + n01, r11 + n11);
            r00 = m00; r01 = m01; r10 = m10; r11 = m11;
        }
        float4 v; v.x = r00; v.y = r01; v.z = r10; v.w = r11;
        *(float4*)(Q + ((size_t)c * 1536 + s) * 4) = v;
    } else if (t0 <= len - 1) {
        // boundary chunk: walk from end-state at len-1 down to t0 (statically unrolled)
        float X = 0.f, Y = IMP;
#pragma unroll
        for (int j = 6; j >= 0; --j) {
            if (t0 + j <= len - 2) {
                float g0 = e[j + 1][0], g1 = e[j + 1][1], g2 = e[j + 1][2], g3 = e[j + 1][3],
                      g4 = e[j + 1][4];
                float nX = lse2(lse2(g0, g4) + X, g2 + Y);
                float nY = lse2(g3 + X, g1 + Y);
                X = nX; Y = nY;
            }
        }
        float2 v; v.x = X; v.y = Y;
        *(float2*)(BS + ((size_t)c * 1536 + s) * 2) = v;
    }
}

// ---------------- sequential combine over 128 chunks per sequence -------------
__global__ __launch_bounds__(64) void combine_kernel(const float* __restrict__ P,
                                                     const float* __restrict__ Q,
                                                     const int* __restrict__ lens,
                                                     float* __restrict__ FS,
                                                     float* __restrict__ BS) {
    int s = blockIdx.x * 64 + threadIdx.x;
    float x = 0.f, y = IMP;
    for (int c = 0; c < 128; ++c) {
        float2 v; v.x = x; v.y = y;
        *(float2*)(FS + ((size_t)c * 1536 + s) * 2) = v;
        float4 p = *(const float4*)(P + ((size_t)c * 1536 + s) * 4);
        float nx = lse2(p.x + x, p.y + y);
        float ny = lse2(p.z + x, p.w + y);
        x = nx; y = ny;
    }
    int len = lens[s / 24];
    int cb = (len - 1) >> 3;
    float2 b = *(const float2*)(BS + ((size_t)cb * 1536 + s) * 2);
    float X = b.x, Y = b.y;
    for (int c = cb - 1; c >= 0; --c) {
        float4 q = *(const float4*)(Q + ((size_t)c * 1536 + s) * 4);
        float nX = lse2(q.x + X, q.y + Y);
        float nY = lse2(q.z + X, q.w + Y);
        X = nX; Y = nY;
        float2 v; v.x = X; v.y = Y;
        *(float2*)(BS + ((size_t)c * 1536 + s) * 2) = v;
    }
}

// ---------------- fused replay + loss, chunk=8 --------------------------------
__global__ __launch_bounds__(256) void loss_kernel(const float* __restrict__ E,
                                                   const int* __restrict__ lens,
                                                   const float* __restrict__ FS,
                                                   const float* __restrict__ BS,
                                                   const int* __restrict__ tagsT,
                                                   double* __restrict__ acc) {
    int s = blockIdx.x * 256 + threadIdx.x;
    int c = blockIdx.y;                      // 0..127
    int t0 = c << 3;
    int len = lens[s / 24];
    double Lv = 0.0;

    if (t0 < len) {
        int cb = (len - 1) >> 3;
        int nt = min(8, len - t0);
        const float* ep = E + (size_t)t0 * 7680 + s * 5;

        float ev[8][5];
#pragma unroll
        for (int j = 0; j < 8; ++j) {
            if (j < nt) {
                const float* q = ep + (size_t)j * 7680;
                ev[j][0] = q[0]; ev[j][1] = q[1]; ev[j][2] = q[2]; ev[j][3] = q[3]; ev[j][4] = q[4];
            }
        }
        float e8[5] = {0.f, 0.f, 0.f, 0.f, 0.f};
        if (c < cb) {
            const float* q = ep + (size_t)8 * 7680;
            e8[0] = q[0]; e8[1] = q[1]; e8[2] = q[2]; e8[3] = q[3]; e8[4] = q[4];
        }
        int tg[8];
#pragma unroll
        for (int j = 0; j < 8; ++j) tg[j] = tagsT[(size_t)(t0 + j) * 1536 + s];  // coalesced

        // forward replay
        float2 f = *(const float2*)(FS + ((size_t)c * 1536 + s) * 2);
        float x = f.x, y = f.y;
        float xs[8], ys[8];
#pragma unroll
        for (int j = 0; j < 8; ++j) {
            if (j < nt) {
                xs[j] = x; ys[j] = y;
                float nx = lse2(lse2(ev[j][0], ev[j][4]) + x, ev[j][3] + y);
                float ny = lse2(ev[j][2] + x, ev[j][1] + y);
                x = nx; y = ny;
            }
        }

        // backward replay + loss (E values already in registers)
        float X = 0.f, Y = IMP;
        if (c < cb) {
            float2 bb = *(const float2*)(BS + ((size_t)(c + 1) * 1536 + s) * 2);
            X = bb.x; Y = bb.y;
        }
#pragma unroll
        for (int j = 7; j >= 0; --j) {
            if (j >= nt) continue;
            if (c == cb && j == nt - 1) {
                X = 0.f; Y = IMP;  // beta_{len-1} = end
            } else {
                float g0, g1, g2, g3, g4;
                if (j == 7) { g0 = e8[0]; g1 = e8[1]; g2 = e8[2]; g3 = e8[3]; g4 = e8[4]; }
                else { g0 = ev[j + 1][0]; g1 = ev[j + 1][1]; g2 = ev[j + 1][2];
                       g3 = ev[j + 1][3]; g4 = ev[j + 1][4]; }
                float nX = lse2(lse2(g0, g4) + X, g2 + Y);
                float nY = lse2(g3 + X, g1 + Y);
                X = nX; Y = nY;
            }
            float v0 = xs[j] + ev[j][0] + X, v1 = ys[j] + ev[j][1] + Y, v2 = xs[j] + ev[j][2] + Y;
            float v3 = ys[j] + ev[j][3] + X, v4 = xs[j] + ev[j][4] + X;
            int tag = tg[j];
            float m = fmaxf(fmaxf(fmaxf(fmaxf(v0, v1), v2), v3), v4);
            float ssum = __expf(v0 - m) + __expf(v1 - m) + __expf(v2 - m) +
                         __expf(v3 - m) + __expf(v4 - m);
            float lse = m + __logf(ssum);
            float vt = (tag == 0) ? v0 : (tag == 1) ? v1 : (tag == 2) ? v2 : (tag == 3) ? v3 : v4;
            float ls = vt - lse;
            float mm = fmaxf(ls, IMP);
            float term = mm + __logf(__expf(ls - mm) + 4.0f * __expf(IMP - mm));
            Lv += (double)term;
        }
    }

    __shared__ double red[256];
    red[threadIdx.x] = Lv;
    __syncthreads();
    for (int st = 128; st > 0; st >>= 1) {
        if (threadIdx.x < st) red[threadIdx.x] += red[threadIdx.x + st];
        __syncthreads();
    }
    if (threadIdx.x == 0) atomicAdd(acc, red[0]);
}

__global__ void finalize_kernel(const double* __restrict__ acc, float* __restrict__ out) {
    out[0] = (float)(-(*acc) * 0.01);
}

// ---------------- launcher ----------------------------------------------------
extern "C" void kernel_launch(void* const* d_in, const int* in_sizes, int n_in,
                              void* d_out, int out_size, void* d_ws, size_t ws_size,
                              hipStream_t stream) {
    const float* embeds = (const float*)d_in[0];
    const float* W = (const float*)d_in[1];
    const float* bias = (const float*)d_in[2];
    const unsigned char* mask = (const unsigned char*)d_in[3];
    const int* tags = (const int*)d_in[4];
    float* out = (float*)d_out;

    char* ws = (char*)d_ws;
    short* Bh = (short*)(ws + O_BH);
    short* Bl = (short*)(ws + O_BL);
    int* lens = (int*)(ws + O_LEN);
    double* acc = (double*)(ws + O_ACC);
    int* tagsT = (int*)(ws + O_TT);
    float* E = (float*)(ws + O_E);
    float* P = (float*)(ws + O_P);
    float* Q = (float*)(ws + O_Q);
    float* FS = (float*)(ws + O_FS);
    float* BS = (float*)(ws + O_BS);

    prep_kernel<<<64, 256, 0, stream>>>(mask, lens, acc);
    prepW_kernel<<<256, 256, 0, stream>>>(W, Bh, Bl);
    tagsT_kernel<<<6144, 256, 0, stream>>>(tags, tagsT);
    mfma_gemm<<<512, 256, 0, stream>>>(embeds, Bh, Bl, bias, E);
    chunkops_kernel<<<dim3(6, 128), 256, 0, stream>>>(E, lens, P, Q, BS);
    combine_kernel<<<24, 64, 0, stream>>>(P, Q, lens, FS, BS);
    loss_kernel<<<dim3(6, 128), 256, 0, stream>>>(E, lens, FS, BS, tagsT, acc);
    finalize_kernel<<<1, 1, 0, stream>>>(acc, out);
}

// Round 13
// 273.810 us; speedup vs baseline: 3.5041x; 1.2048x over previous
//
#include <hip/hip_runtime.h>
#include <hip/hip_bf16.h>

#define IMP -10000.0f

// ws layout (bytes)
#define O_BH   0u          // Bhi: 128*512 bf16 = 131072
#define O_BL   131072u     // Blo -> ends 262144
#define O_LEN  262144u     // 64 ints (+pad)
#define O_ACC  262400u     // 1 double (+pad)
#define O_TT   262656u     // tagsT [1024][1536] i32 = 6291456 -> ends 6554112
#define O_E    6554112u    // [1024][1536][5] f = 31457280 -> ends 38011392
#define O_P    38011392u   // [128][1536][4] f = 3145728  -> ends 41157120
#define O_Q    41157120u   // [128][1536][4] f = 3145728  -> ends 44302848
#define O_FS   44302848u   // [128][1536][2] f = 1572864  -> ends 45875712
#define O_BS   45875712u   // [128][1536][2] f = 1572864  -> ends 47448576

typedef __attribute__((ext_vector_type(8))) short bf16x8;
typedef __attribute__((ext_vector_type(4))) float f32x4;

__device__ __forceinline__ float lse2(float a, float b) {
    float m = fmaxf(a, b);
    return m + __logf(__expf(a - m) + __expf(b - m));
}

// 2x2 log-semiring matrix product A x B; layout (x=m00, y=m01, z=m10, w=m11)
__device__ __forceinline__ float4 matmul22(float4 A, float4 B) {
    float4 r;
    r.x = lse2(A.x + B.x, A.y + B.z);
    r.y = lse2(A.x + B.y, A.y + B.w);
    r.z = lse2(A.z + B.x, A.w + B.z);
    r.w = lse2(A.z + B.y, A.w + B.w);
    return r;
}

// float -> bf16 round-to-nearest-even (bit trick; inputs are finite)
__device__ __forceinline__ unsigned short f2bf(float x) {
    unsigned u = __float_as_uint(x);
    return (unsigned short)((u + 0x7FFFu + ((u >> 16) & 1u)) >> 16);
}
__device__ __forceinline__ float bf2f(unsigned short h) {
    return __uint_as_float(((unsigned)h) << 16);
}

// ---------------- prep: lengths from mask + zero accumulator ------------------
__global__ __launch_bounds__(256) void prep_kernel(const unsigned char* __restrict__ mask,
                                                   int* __restrict__ lens,
                                                   double* __restrict__ acc) {
    int n = blockIdx.x;
    int tid = threadIdx.x;
    bool i32 = (mask[1] == 0);  // mask[0][1] always true (len>=512): u8->1, i32->byte1==0
    int cnt = 0;
    if (i32) {
        const int* m = (const int*)mask;
        for (int t = tid; t < 1024; t += 256) cnt += (m[n * 1024 + t] != 0);
    } else {
        for (int t = tid; t < 1024; t += 256) cnt += (mask[n * 1024 + t] != 0);
    }
    __shared__ int red[256];
    red[tid] = cnt;
    __syncthreads();
    for (int s = 128; s > 0; s >>= 1) {
        if (tid < s) red[tid] += red[tid + s];
        __syncthreads();
    }
    if (tid == 0) {
        lens[n] = red[0];
        if (n == 0) *acc = 0.0;
    }
}

// ---------------- tags [s][t] -> tagsT [t][s] (coalesced writes) --------------
__global__ __launch_bounds__(256) void tagsT_kernel(const int* __restrict__ tags,
                                                    int* __restrict__ tagsT) {
    int idx = blockIdx.x * 256 + threadIdx.x;   // 0..1572863
    int t = idx / 1536, s = idx - t * 1536;
    tagsT[idx] = tags[(size_t)s * 1024 + t];
}

// ---------------- W -> split bf16, B-fragment-swizzled layout -----------------
__global__ __launch_bounds__(256) void prepW_kernel(const float* __restrict__ W,
                                                    short* __restrict__ Bh,
                                                    short* __restrict__ Bl) {
    int idx = blockIdx.x * 256 + threadIdx.x;  // 0..65535
    int col = idx >> 9, k = idx & 511;
    float v = (col < 120) ? W[col * 512 + k] : 0.f;
    unsigned short h = f2bf(v);
    unsigned short l = f2bf(v - bf2f(h));
    int ct = col >> 4, c = col & 15;
    int kt = k >> 5, kg = (k >> 3) & 3, i = k & 7;
    size_t flat = ((size_t)(kt * 8 + ct) * 64 + kg * 16 + c) * 8 + i;
    Bh[flat] = (short)h;
    Bl[flat] = (short)l;
}

// ---------------- split-bf16 MFMA GEMM: E = embeds @ W^T + bias ---------------
__global__ __launch_bounds__(256) void mfma_gemm(const float* __restrict__ A,
                                                 const short* __restrict__ Bh,
                                                 const short* __restrict__ Bl,
                                                 const float* __restrict__ bias,
                                                 float* __restrict__ E) {
    __shared__ short Ah[4][128][8];
    __shared__ short Al[4][128][8];
    int tid = threadIdx.x;
    int wave = tid >> 6, lane = tid & 63;
    long r0 = (long)blockIdx.x * 128;

    f32x4 acc[8][2];
#pragma unroll
    for (int rt = 0; rt < 8; ++rt)
#pragma unroll
        for (int ci = 0; ci < 2; ++ci) {
            acc[rt][ci][0] = 0.f; acc[rt][ci][1] = 0.f;
            acc[rt][ci][2] = 0.f; acc[rt][ci][3] = 0.f;
        }

    float bb[2];
#pragma unroll
    for (int ci = 0; ci < 2; ++ci) {
        int col = wave * 32 + ci * 16 + (lane & 15);
        bb[ci] = (col < 120) ? bias[col] : 0.f;
    }

    int arow = lane & 15;
    int akg = lane >> 4;

    for (int kt = 0; kt < 16; ++kt) {
        __syncthreads();
#pragma unroll
        for (int i = 0; i < 4; ++i) {
            int f = tid + (i << 8);
            int row = f >> 3, fq = f & 7;
            const float4 v = *(const float4*)(A + (r0 + row) * 512 + kt * 32 + fq * 4);
            int kgw = fq >> 1, i0 = (fq & 1) * 4;
            unsigned short h0 = f2bf(v.x), h1 = f2bf(v.y), h2 = f2bf(v.z), h3 = f2bf(v.w);
            short4 hv = make_short4((short)h0, (short)h1, (short)h2, (short)h3);
            short4 lv = make_short4((short)f2bf(v.x - bf2f(h0)), (short)f2bf(v.y - bf2f(h1)),
                                    (short)f2bf(v.z - bf2f(h2)), (short)f2bf(v.w - bf2f(h3)));
            *(short4*)&Ah[kgw][row][i0] = hv;
            *(short4*)&Al[kgw][row][i0] = lv;
        }
        __syncthreads();

        bf16x8 bh[2], bl[2];
#pragma unroll
        for (int ci = 0; ci < 2; ++ci) {
            int ct = wave * 2 + ci;
            size_t base = ((size_t)(kt * 8 + ct) * 64 + lane) * 8;
            bh[ci] = *(const bf16x8*)(Bh + base);
            bl[ci] = *(const bf16x8*)(Bl + base);
        }

#pragma unroll
        for (int rt = 0; rt < 8; ++rt) {
            bf16x8 ah = *(const bf16x8*)&Ah[akg][rt * 16 + arow][0];
            bf16x8 al = *(const bf16x8*)&Al[akg][rt * 16 + arow][0];
#pragma unroll
            for (int ci = 0; ci < 2; ++ci) {
                acc[rt][ci] = __builtin_amdgcn_mfma_f32_16x16x32_bf16(ah, bh[ci], acc[rt][ci], 0, 0, 0);
                acc[rt][ci] = __builtin_amdgcn_mfma_f32_16x16x32_bf16(ah, bl[ci], acc[rt][ci], 0, 0, 0);
                acc[rt][ci] = __builtin_amdgcn_mfma_f32_16x16x32_bf16(al, bh[ci], acc[rt][ci], 0, 0, 0);
            }
        }
    }

#pragma unroll
    for (int rt = 0; rt < 8; ++rt) {
#pragma unroll
        for (int ci = 0; ci < 2; ++ci) {
            int col = wave * 32 + ci * 16 + (lane & 15);
            if (col < 120) {
#pragma unroll
                for (int j = 0; j < 4; ++j) {
                    long r = r0 + rt * 16 + (lane >> 4) * 4 + j;  // r = n*1024 + t
                    int n = (int)(r >> 10), t = (int)(r & 1023);
                    E[(size_t)t * 7680 + n * 120 + col] = acc[rt][ci][j] + bb[ci];
                }
            }
        }
    }
}

// ---------------- fused chunk operators, chunk=8 (2x2 log-semiring) -----------
// fwd step t: M_t = [[lse2(e0,e4), e3],[e2, e1]] from e_t;  state' = M*state
// bwd step t: N_t = [[lse2(e0,e4), e2],[e3, e1]] from e_{t+1}; beta_t = N_t*beta_{t+1}
__global__ __launch_bounds__(256) void chunkops_kernel(const float* __restrict__ E,
                                                       const int* __restrict__ lens,
                                                       float* __restrict__ P,
                                                       float* __restrict__ Q,
                                                       float* __restrict__ BS) {
    int s = blockIdx.x * 256 + threadIdx.x;  // 0..1535
    int c = blockIdx.y;                      // 0..127
    int t0 = c << 3;
    int len = lens[s / 24];
    const float* ep = E + (size_t)t0 * 7680 + s * 5;
    bool fullQ = (t0 + 8 <= len - 1);

    float e[9][5];
#pragma unroll
    for (int j = 0; j < 8; ++j) {
        const float* q = ep + (size_t)j * 7680;
        e[j][0] = q[0]; e[j][1] = q[1]; e[j][2] = q[2]; e[j][3] = q[3]; e[j][4] = q[4];
    }
    if (fullQ) {
        const float* q = ep + (size_t)8 * 7680;
        e[8][0] = q[0]; e[8][1] = q[1]; e[8][2] = q[2]; e[8][3] = q[3]; e[8][4] = q[4];
    }

    // forward chunk operator: P_c = M_{t0+7} x ... x M_{t0}
    {
        float r00 = lse2(e[0][0], e[0][4]), r01 = e[0][3], r10 = e[0][2], r11 = e[0][1];
#pragma unroll
        for (int j = 1; j < 8; ++j) {
            float m00 = lse2(e[j][0], e[j][4]), m01 = e[j][3], m10 = e[j][2], m11 = e[j][1];
            float n00 = lse2(m00 + r00, m01 + r10);
            float n01 = lse2(m00 + r01, m01 + r11);
            float n10 = lse2(m10 + r00, m11 + r10);
            float n11 = lse2(m10 + r01, m11 + r11);
            r00 = n00; r01 = n01; r10 = n10; r11 = n11;
        }
        float4 v; v.x = r00; v.y = r01; v.z = r10; v.w = r11;
        *(float4*)(P + ((size_t)c * 1536 + s) * 4) = v;
    }

    if (fullQ) {
        // Q_c = N_{t0} x N_{t0+1} x ... x N_{t0+7}
        float r00 = lse2(e[1][0], e[1][4]), r01 = e[1][2], r10 = e[1][3], r11 = e[1][1];
#pragma unroll
        for (int j = 1; j < 8; ++j) {
            float g0 = e[j + 1][0], g1 = e[j + 1][1], g2 = e[j + 1][2], g3 = e[j + 1][3],
                  g4 = e[j + 1][4];
            float n00 = lse2(g0, g4), n01 = g2, n10 = g3, n11 = g1;
            float m00 = lse2(r00 + n00, r01 + n10);
            float m01 = lse2(r00 + n01, r01 + n11);
            float m10 = lse2(r10 + n00, r11 + n10);
            float m11 = lse2(r10 + n01, r11 + n11);
            r00 = m00; r01 = m01; r10 = m10; r11 = m11;
        }
        float4 v; v.x = r00; v.y = r01; v.z = r10; v.w = r11;
        *(float4*)(Q + ((size_t)c * 1536 + s) * 4) = v;
    } else if (t0 <= len - 1) {
        // boundary chunk: walk from end-state at len-1 down to t0 (statically unrolled)
        float X = 0.f, Y = IMP;
#pragma unroll
        for (int j = 6; j >= 0; --j) {
            if (t0 + j <= len - 2) {
                float g0 = e[j + 1][0], g1 = e[j + 1][1], g2 = e[j + 1][2], g3 = e[j + 1][3],
                      g4 = e[j + 1][4];
                float nX = lse2(lse2(g0, g4) + X, g2 + Y);
                float nY = lse2(g3 + X, g1 + Y);
                X = nX; Y = nY;
            }
        }
        float2 v; v.x = X; v.y = Y;
        *(float2*)(BS + ((size_t)c * 1536 + s) * 2) = v;
    }
}

// ---------------- parallel combine: Kogge-Stone scan over 128 chunks ----------
// one block (128 threads) per sequence; 7 levels of 2x2 log-semiring composes.
__global__ __launch_bounds__(128) void combine_kernel(const float* __restrict__ P,
                                                      const float* __restrict__ Q,
                                                      const int* __restrict__ lens,
                                                      float* __restrict__ FS,
                                                      float* __restrict__ BS) {
    int s = blockIdx.x;      // 0..1535
    int c = threadIdx.x;     // 0..127
    __shared__ float4 ops[128];

    // ---- forward: inclusive prefix product incl[c] = P_c x P_{c-1} x ... x P_0
    float4 v = *(const float4*)(P + ((size_t)c * 1536 + s) * 4);
    ops[c] = v;
    __syncthreads();
#pragma unroll
    for (int d = 1; d < 128; d <<= 1) {
        float4 other;
        bool act = (c >= d);
        if (act) other = ops[c - d];
        __syncthreads();
        if (act) { v = matmul22(v, other); ops[c] = v; }
        __syncthreads();
    }
    // FS[c] = incl[c-1] applied to init (0, IMP); FS[0] = init
    float2 fs;
    if (c == 0) {
        fs.x = 0.f; fs.y = IMP;
    } else {
        float4 m = ops[c - 1];
        fs.x = lse2(m.x, m.y + IMP);
        fs.y = lse2(m.z, m.w + IMP);
    }
    *(float2*)(FS + ((size_t)c * 1536 + s) * 2) = fs;

    // ---- backward: suffix product T_c = R_c x ... x R_127, R_c = Q_c (c<cb) else I
    int len = lens[s / 24];
    int cb = (len - 1) >> 3;
    float2 b = *(const float2*)(BS + ((size_t)cb * 1536 + s) * 2);  // from chunkops
    __syncthreads();  // fwd ops reads complete before overwrite

    float4 r;
    if (c < cb) {
        r = *(const float4*)(Q + ((size_t)c * 1536 + s) * 4);
    } else {
        r.x = 0.f; r.y = IMP; r.z = IMP; r.w = 0.f;  // identity
    }
    ops[c] = r;
    __syncthreads();
#pragma unroll
    for (int d = 1; d < 128; d <<= 1) {
        float4 other;
        bool act = (c + d) < 128;
        if (act) other = ops[c + d];
        __syncthreads();
        if (act) { r = matmul22(r, other); ops[c] = r; }
        __syncthreads();
    }
    if (c < cb) {
        float2 bs;
        bs.x = lse2(r.x + b.x, r.y + b.y);
        bs.y = lse2(r.z + b.x, r.w + b.y);
        *(float2*)(BS + ((size_t)c * 1536 + s) * 2) = bs;
    }
}

// ---------------- fused replay + loss, chunk=8 --------------------------------
__global__ __launch_bounds__(256) void loss_kernel(const float* __restrict__ E,
                                                   const int* __restrict__ lens,
                                                   const float* __restrict__ FS,
                                                   const float* __restrict__ BS,
                                                   const int* __restrict__ tagsT,
                                                   double* __restrict__ acc) {
    int s = blockIdx.x * 256 + threadIdx.x;
    int c = blockIdx.y;                      // 0..127
    int t0 = c << 3;
    int len = lens[s / 24];
    double Lv = 0.0;

    if (t0 < len) {
        int cb = (len - 1) >> 3;
        int nt = min(8, len - t0);
        const float* ep = E + (size_t)t0 * 7680 + s * 5;

        float ev[8][5];
#pragma unroll
        for (int j = 0; j < 8; ++j) {
            if (j < nt) {
                const float* q = ep + (size_t)j * 7680;
                ev[j][0] = q[0]; ev[j][1] = q[1]; ev[j][2] = q[2]; ev[j][3] = q[3]; ev[j][4] = q[4];
            }
        }
        float e8[5] = {0.f, 0.f, 0.f, 0.f, 0.f};
        if (c < cb) {
            const float* q = ep + (size_t)8 * 7680;
            e8[0] = q[0]; e8[1] = q[1]; e8[2] = q[2]; e8[3] = q[3]; e8[4] = q[4];
        }
        int tg[8];
#pragma unroll
        for (int j = 0; j < 8; ++j) tg[j] = tagsT[(size_t)(t0 + j) * 1536 + s];  // coalesced

        // forward replay
        float2 f = *(const float2*)(FS + ((size_t)c * 1536 + s) * 2);
        float x = f.x, y = f.y;
        float xs[8], ys[8];
#pragma unroll
        for (int j = 0; j < 8; ++j) {
            if (j < nt) {
                xs[j] = x; ys[j] = y;
                float nx = lse2(lse2(ev[j][0], ev[j][4]) + x, ev[j][3] + y);
                float ny = lse2(ev[j][2] + x, ev[j][1] + y);
                x = nx; y = ny;
            }
        }

        // backward replay + loss (E values already in registers)
        float X = 0.f, Y = IMP;
        if (c < cb) {
            float2 bb = *(const float2*)(BS + ((size_t)(c + 1) * 1536 + s) * 2);
            X = bb.x; Y = bb.y;
        }
#pragma unroll
        for (int j = 7; j >= 0; --j) {
            if (j >= nt) continue;
            if (c == cb && j == nt - 1) {
                X = 0.f; Y = IMP;  // beta_{len-1} = end
            } else {
                float g0, g1, g2, g3, g4;
                if (j == 7) { g0 = e8[0]; g1 = e8[1]; g2 = e8[2]; g3 = e8[3]; g4 = e8[4]; }
                else { g0 = ev[j + 1][0]; g1 = ev[j + 1][1]; g2 = ev[j + 1][2];
                       g3 = ev[j + 1][3]; g4 = ev[j + 1][4]; }
                float nX = lse2(lse2(g0, g4) + X, g2 + Y);
                float nY = lse2(g3 + X, g1 + Y);
                X = nX; Y = nY;
            }
            float v0 = xs[j] + ev[j][0] + X, v1 = ys[j] + ev[j][1] + Y, v2 = xs[j] + ev[j][2] + Y;
            float v3 = ys[j] + ev[j][3] + X, v4 = xs[j] + ev[j][4] + X;
            int tag = tg[j];
            float m = fmaxf(fmaxf(fmaxf(fmaxf(v0, v1), v2), v3), v4);
            float ssum = __expf(v0 - m) + __expf(v1 - m) + __expf(v2 - m) +
                         __expf(v3 - m) + __expf(v4 - m);
            float lse = m + __logf(ssum);
            float vt = (tag == 0) ? v0 : (tag == 1) ? v1 : (tag == 2) ? v2 : (tag == 3) ? v3 : v4;
            float ls = vt - lse;
            float mm = fmaxf(ls, IMP);
            float term = mm + __logf(__expf(ls - mm) + 4.0f * __expf(IMP - mm));
            Lv += (double)term;
        }
    }

    __shared__ double red[256];
    red[threadIdx.x] = Lv;
    __syncthreads();
    for (int st = 128; st > 0; st >>= 1) {
        if (threadIdx.x < st) red[threadIdx.x] += red[threadIdx.x + st];
        __syncthreads();
    }
    if (threadIdx.x == 0) atomicAdd(acc, red[0]);
}

__global__ void finalize_kernel(const double* __restrict__ acc, float* __restrict__ out) {
    out[0] = (float)(-(*acc) * 0.01);
}

// ---------------- launcher ----------------------------------------------------
extern "C" void kernel_launch(void* const* d_in, const int* in_sizes, int n_in,
                              void* d_out, int out_size, void* d_ws, size_t ws_size,
                              hipStream_t stream) {
    const float* embeds = (const float*)d_in[0];
    const float* W = (const float*)d_in[1];
    const float* bias = (const float*)d_in[2];
    const unsigned char* mask = (const unsigned char*)d_in[3];
    const int* tags = (const int*)d_in[4];
    float* out = (float*)d_out;

    char* ws = (char*)d_ws;
    short* Bh = (short*)(ws + O_BH);
    short* Bl = (short*)(ws + O_BL);
    int* lens = (int*)(ws + O_LEN);
    double* acc = (double*)(ws + O_ACC);
    int* tagsT = (int*)(ws + O_TT);
    float* E = (float*)(ws + O_E);
    float* P = (float*)(ws + O_P);
    float* Q = (float*)(ws + O_Q);
    float* FS = (float*)(ws + O_FS);
    float* BS = (float*)(ws + O_BS);

    prep_kernel<<<64, 256, 0, stream>>>(mask, lens, acc);
    prepW_kernel<<<256, 256, 0, stream>>>(W, Bh, Bl);
    tagsT_kernel<<<6144, 256, 0, stream>>>(tags, tagsT);
    mfma_gemm<<<512, 256, 0, stream>>>(embeds, Bh, Bl, bias, E);
    chunkops_kernel<<<dim3(6, 128), 256, 0, stream>>>(E, lens, P, Q, BS);
    combine_kernel<<<1536, 128, 0, stream>>>(P, Q, lens, FS, BS);
    loss_kernel<<<dim3(6, 128), 256, 0, stream>>>(E, lens, FS, BS, tagsT, acc);
    finalize_kernel<<<1, 1, 0, stream>>>(acc, out);
}